// Round 1
// baseline (1677.923 us; speedup 1.0000x reference)
//
#include <hip/hip_runtime.h>
#include <hip/hip_bf16.h>
#include <cstdint>

// Problem constants
#define NB 128
#define LL 384   // LP == LH == 384
#define DD 768
#define NEG_BIAS 1e13f

typedef __attribute__((ext_vector_type(8))) short bf16x8;
typedef __attribute__((ext_vector_type(4))) float f32x4;

// ---------- bf16 helpers (RNE, matches HW conversion) ----------
__device__ __forceinline__ unsigned short f2bf(float f) {
  unsigned int u = __float_as_uint(f);
  return (unsigned short)((u + 0x7fffu + ((u >> 16) & 1u)) >> 16);
}
__device__ __forceinline__ float bf2f(unsigned short v) {
  return __uint_as_float(((unsigned int)v) << 16);
}
__device__ __forceinline__ void split2(float f, unsigned short& h, unsigned short& l) {
  h = f2bf(f);
  l = f2bf(f - bf2f(h));
}

// ---------- shared MFMA tile core ----------
// LDS planes: [128 rows][64 k] bf16, row pitch 128 B, 16B-slot XOR swizzle: slot ^= (row&7)
__device__ __forceinline__ void mfma3(f32x4& acc, bf16x8 ah, bf16x8 al, bf16x8 bh, bf16x8 bl) {
  acc = __builtin_amdgcn_mfma_f32_16x16x32_bf16(ah, bh, acc, 0, 0, 0);
  acc = __builtin_amdgcn_mfma_f32_16x16x32_bf16(ah, bl, acc, 0, 0, 0);
  acc = __builtin_amdgcn_mfma_f32_16x16x32_bf16(al, bh, acc, 0, 0, 0);
}

__device__ __forceinline__ void compute_tile(const char* AH, const char* AL,
                                             const char* BH, const char* BL,
                                             int lane, int wr, int wc, f32x4 (&acc)[4][4]) {
  const int q16 = (lane >> 4) * 16;   // 16B k-slot base within 64-k row (x2 ks)
  const int r15 = lane & 15;
#pragma unroll
  for (int ks = 0; ks < 2; ++ks) {
    bf16x8 ah[4], al[4], bh[4], bl[4];
    int koff = ks * 64 + q16;
#pragma unroll
    for (int i = 0; i < 4; ++i) {
      int ar = wr + i * 16 + r15;
      int ao = ar * 128 + (koff ^ ((ar & 7) << 4));
      ah[i] = *(const bf16x8*)(AH + ao);
      al[i] = *(const bf16x8*)(AL + ao);
      int br = wc + i * 16 + r15;
      int bo = br * 128 + (koff ^ ((br & 7) << 4));
      bh[i] = *(const bf16x8*)(BH + bo);
      bl[i] = *(const bf16x8*)(BL + bo);
    }
#pragma unroll
    for (int i = 0; i < 4; ++i)
#pragma unroll
      for (int j = 0; j < 4; ++j)
        mfma3(acc[i][j], ah[i], al[i], bh[j], bl[j]);
  }
}

// ---------- kernel 1: transpose + bf16 hi/lo split ----------
// X: [B][384][768] fp32  ->  TH/TL: [B][768][384] bf16 bits
__global__ __launch_bounds__(256) void transpose_split(
    const float* __restrict__ X, unsigned short* __restrict__ TH, unsigned short* __restrict__ TL) {
  __shared__ float lds[32][33];
  int b = blockIdx.x, ti = blockIdx.y, tj = blockIdx.z;
  int l0 = ti * 32, d0 = tj * 32;
  int t = threadIdx.x;
  int r = t >> 5, c = t & 31;
#pragma unroll
  for (int k = 0; k < 4; ++k) {
    int rr = r + k * 8;
    lds[rr][c] = X[((size_t)b * LL + l0 + rr) * DD + d0 + c];
  }
  __syncthreads();
#pragma unroll
  for (int k = 0; k < 4; ++k) {
    int rr = r + k * 8;                       // local d index
    float v = lds[c][rr];                     // X[b][l0+c][d0+rr]
    unsigned short h, l;
    split2(v, h, l);
    size_t o = ((size_t)b * DD + d0 + rr) * LL + l0 + c;
    TH[o] = h;
    TL[o] = l;
  }
}

// ---------- kernel 2: sim = pre @ hypo^T (per batch), fp32 out via bf16x3 split ----------
__global__ __launch_bounds__(256, 2) void sim_gemm(
    const float* __restrict__ pre, const float* __restrict__ hypo, float* __restrict__ sim) {
  int blk = blockIdx.x;
  int b = blk / 9, tt = blk % 9;
  int tp = tt / 3, th = tt % 3;
  int t = threadIdx.x, lane = t & 63, w = t >> 6;
  int wr = (w >> 1) * 64, wc = (w & 1) * 64;
  __shared__ char lds[65536];
  char *AH = lds, *AL = lds + 16384, *BH = lds + 32768, *BL = lds + 49152;
  const float* Ag = pre + ((size_t)b * LL + tp * 128) * DD;
  const float* Bg = hypo + ((size_t)b * LL + th * 128) * DD;
  int srow = t >> 4, sc4 = t & 15;

  f32x4 acc[4][4];
#pragma unroll
  for (int i = 0; i < 4; ++i)
#pragma unroll
    for (int j = 0; j < 4; ++j) acc[i][j] = (f32x4){0.f, 0.f, 0.f, 0.f};

  auto load16 = [&](float4 (&av)[8], float4 (&bv)[8], int k0) {
#pragma unroll
    for (int pass = 0; pass < 8; ++pass) {
      int rr = pass * 16 + srow;
      av[pass] = *(const float4*)(Ag + (size_t)rr * DD + k0 + sc4 * 4);
      bv[pass] = *(const float4*)(Bg + (size_t)rr * DD + k0 + sc4 * 4);
    }
  };
  auto store16 = [&](float4 (&av)[8], float4 (&bv)[8]) {
#pragma unroll
    for (int pass = 0; pass < 8; ++pass) {
      int rr = pass * 16 + srow;
      int off = rr * 128 + ((sc4 * 8) ^ ((rr & 7) << 4));
      unsigned short h0, h1, h2, h3, l0, l1, l2, l3;
      split2(av[pass].x, h0, l0); split2(av[pass].y, h1, l1);
      split2(av[pass].z, h2, l2); split2(av[pass].w, h3, l3);
      *(uint2*)(AH + off) = make_uint2(((unsigned)h1 << 16) | h0, ((unsigned)h3 << 16) | h2);
      *(uint2*)(AL + off) = make_uint2(((unsigned)l1 << 16) | l0, ((unsigned)l3 << 16) | l2);
      split2(bv[pass].x, h0, l0); split2(bv[pass].y, h1, l1);
      split2(bv[pass].z, h2, l2); split2(bv[pass].w, h3, l3);
      *(uint2*)(BH + off) = make_uint2(((unsigned)h1 << 16) | h0, ((unsigned)h3 << 16) | h2);
      *(uint2*)(BL + off) = make_uint2(((unsigned)l1 << 16) | l0, ((unsigned)l3 << 16) | l2);
    }
  };

  float4 avA[8], bvA[8], avB[8], bvB[8];
  load16(avA, bvA, 0);
  for (int kt = 0; kt < 12; kt += 2) {
    __syncthreads();
    store16(avA, bvA);
    if (kt + 1 < 12) load16(avB, bvB, (kt + 1) * 64);
    __syncthreads();
    compute_tile(AH, AL, BH, BL, lane, wr, wc, acc);
    __syncthreads();
    store16(avB, bvB);
    if (kt + 2 < 12) load16(avA, bvA, (kt + 2) * 64);
    __syncthreads();
    compute_tile(AH, AL, BH, BL, lane, wr, wc, acc);
  }

  float* Cg = sim + (size_t)b * (LL * LL);
  int rbase = tp * 128 + wr + ((lane >> 4) << 2);
  int cbase = th * 128 + wc + (lane & 15);
#pragma unroll
  for (int i = 0; i < 4; ++i)
#pragma unroll
    for (int j = 0; j < 4; ++j)
#pragma unroll
      for (int r = 0; r < 4; ++r)
        Cg[(size_t)(rbase + i * 16 + r) * LL + cbase + j * 16] = acc[i][j][r];
}

// ---------- kernel 3: row stats (softmax over h with hypo_mask) ----------
__global__ __launch_bounds__(256) void row_stats(
    const float* __restrict__ sim, const float* __restrict__ hmask,
    float* __restrict__ rmax, float* __restrict__ rinv) {
  int gw = blockIdx.x * 4 + (threadIdx.x >> 6);
  int lane = threadIdx.x & 63;
  int b = gw / LL;
  const float* row = sim + (size_t)gw * LL;
  const float* hm = hmask + (size_t)b * LL;
  float x[6];
  float m = -3.0e38f;
#pragma unroll
  for (int i = 0; i < 6; ++i) {
    float s = row[i * 64 + lane];
    float mk = hm[i * 64 + lane];
    x[i] = s * mk + (mk - 1.f) * NEG_BIAS;
    m = fmaxf(m, x[i]);
  }
#pragma unroll
  for (int off = 32; off; off >>= 1) m = fmaxf(m, __shfl_xor(m, off));
  float sum = 0.f;
#pragma unroll
  for (int i = 0; i < 6; ++i) sum += expf(x[i] - m);
#pragma unroll
  for (int off = 32; off; off >>= 1) sum += __shfl_xor(sum, off);
  if (lane == 0) { rmax[gw] = m; rinv[gw] = 1.f / sum; }
}

// ---------- kernel 4: column stats partials (softmax over p with pre_mask) ----------
__global__ __launch_bounds__(384) void col_stats_part(
    const float* __restrict__ sim, const float* __restrict__ pmask,
    float* __restrict__ cmax_p, float* __restrict__ csum_p) {
  int b = blockIdx.x, part = blockIdx.y, h = threadIdx.x;
  const float* S = sim + (size_t)b * (LL * LL);
  const float* pm = pmask + (size_t)b * LL;
  float m = -3.0e38f, s = 0.f;
  int p0 = part * 96;
  for (int p = p0; p < p0 + 96; ++p) {
    float mk = pm[p];
    float xx = S[(size_t)p * LL + h] * mk + (mk - 1.f) * NEG_BIAS;
    float mn = fmaxf(m, xx);
    s = s * expf(m - mn) + expf(xx - mn);
    m = mn;
  }
  size_t o = ((size_t)part * NB + b) * LL + h;
  cmax_p[o] = m;
  csum_p[o] = s;
}

__global__ __launch_bounds__(256) void col_combine(
    const float* __restrict__ cmax_p, const float* __restrict__ csum_p,
    float* __restrict__ cmax, float* __restrict__ cinv) {
  int i = blockIdx.x * 256 + threadIdx.x;  // < 128*384
  const int STRIDE = NB * LL;
  float m = cmax_p[i];
  m = fmaxf(m, cmax_p[STRIDE + i]);
  m = fmaxf(m, cmax_p[2 * STRIDE + i]);
  m = fmaxf(m, cmax_p[3 * STRIDE + i]);
  float s = csum_p[i] * expf(cmax_p[i] - m)
          + csum_p[STRIDE + i] * expf(cmax_p[STRIDE + i] - m)
          + csum_p[2 * STRIDE + i] * expf(cmax_p[2 * STRIDE + i] - m)
          + csum_p[3 * STRIDE + i] * expf(cmax_p[3 * STRIDE + i] - m);
  cmax[i] = m;
  cinv[i] = 1.f / s;
}

// ---------- kernel 5: apply both softmaxes; emit P1 (natural) and P2 (transposed) hi/lo planes ----------
__global__ __launch_bounds__(256) void softmax_apply(
    const float* __restrict__ sim, const float* __restrict__ hmask, const float* __restrict__ pmask,
    const float* __restrict__ rmax, const float* __restrict__ rinv,
    const float* __restrict__ cmax, const float* __restrict__ cinv,
    unsigned short* __restrict__ P1H, unsigned short* __restrict__ P1L,
    unsigned short* __restrict__ P2H, unsigned short* __restrict__ P2L) {
  __shared__ unsigned int lds2[64][65];
  int b = blockIdx.x, tp = blockIdx.y, th = blockIdx.z;
  int p0 = tp * 64, h0 = th * 64;
  int t = threadIdx.x;
  int pr = t >> 4, c4 = t & 15;
  const float* S = sim + (size_t)b * (LL * LL);
  int hbase = h0 + c4 * 4;
  float mh[4], cm[4], ci[4];
#pragma unroll
  for (int i = 0; i < 4; ++i) {
    mh[i] = hmask[(size_t)b * LL + hbase + i];
    cm[i] = cmax[(size_t)b * LL + hbase + i];
    ci[i] = cinv[(size_t)b * LL + hbase + i];
  }
#pragma unroll
  for (int pass = 0; pass < 4; ++pass) {
    int p = p0 + pass * 16 + pr;
    float4 sv = *(const float4*)(S + (size_t)p * LL + hbase);
    float rm = rmax[(size_t)b * LL + p];
    float ri = rinv[(size_t)b * LL + p];
    float mp = pmask[(size_t)b * LL + p];
    float s4[4] = {sv.x, sv.y, sv.z, sv.w};
    unsigned short hh[4], llv[4];
#pragma unroll
    for (int i = 0; i < 4; ++i) {
      float x1 = s4[i] * mh[i] + (mh[i] - 1.f) * NEG_BIAS;
      float p1 = expf(x1 - rm) * ri;
      split2(p1, hh[i], llv[i]);
      float x2 = s4[i] * mp + (mp - 1.f) * NEG_BIAS;
      float p2 = expf(x2 - cm[i]) * ci[i];
      unsigned short h2, l2;
      split2(p2, h2, l2);
      lds2[c4 * 4 + i][pass * 16 + pr] = ((unsigned)h2 << 16) | l2;
    }
    size_t o1 = ((size_t)b * LL + p) * LL + hbase;
    *(uint2*)(P1H + o1) = make_uint2(((unsigned)hh[1] << 16) | hh[0], ((unsigned)hh[3] << 16) | hh[2]);
    *(uint2*)(P1L + o1) = make_uint2(((unsigned)llv[1] << 16) | llv[0], ((unsigned)llv[3] << 16) | llv[2]);
  }
  __syncthreads();
#pragma unroll
  for (int pass = 0; pass < 4; ++pass) {
    int hr = pass * 16 + pr;
    unsigned short hh[4], llv[4];
#pragma unroll
    for (int i = 0; i < 4; ++i) {
      unsigned int v = lds2[hr][c4 * 4 + i];
      hh[i] = (unsigned short)(v >> 16);
      llv[i] = (unsigned short)(v & 0xffffu);
    }
    size_t o2 = ((size_t)b * LL + h0 + hr) * LL + p0 + c4 * 4;
    *(uint2*)(P2H + o2) = make_uint2(((unsigned)hh[1] << 16) | hh[0], ((unsigned)hh[3] << 16) | hh[2]);
    *(uint2*)(P2L + o2) = make_uint2(((unsigned)llv[1] << 16) | llv[0], ((unsigned)llv[3] << 16) | llv[2]);
  }
}

// ---------- kernel 6: out[b][m][d] = (P @ V) * rowmask ----------
// A planes: [B][384][384] (M x K, k contiguous). B planes: [B][768][384] (N x K, k contiguous).
__global__ __launch_bounds__(256, 2) void pv_gemm(
    const unsigned short* __restrict__ AHp, const unsigned short* __restrict__ ALp,
    const unsigned short* __restrict__ BHp, const unsigned short* __restrict__ BLp,
    const float* __restrict__ rowmask, float* __restrict__ out) {
  int b = blockIdx.x, tm = blockIdx.y, tn = blockIdx.z;
  int m0 = tm * 128, n0 = tn * 128;
  int t = threadIdx.x, lane = t & 63, w = t >> 6;
  int wr = (w >> 1) * 64, wc = (w & 1) * 64;
  __shared__ char lds[65536];
  char *AH = lds, *AL = lds + 16384, *BH = lds + 32768, *BL = lds + 49152;
  const unsigned short* Ah = AHp + (size_t)b * (LL * LL) + (size_t)m0 * LL;
  const unsigned short* Al = ALp + (size_t)b * (LL * LL) + (size_t)m0 * LL;
  const unsigned short* Bh = BHp + (size_t)b * (DD * LL) + (size_t)n0 * LL;
  const unsigned short* Bl = BLp + (size_t)b * (DD * LL) + (size_t)n0 * LL;
  int srow = t >> 3, sslot = t & 7;

  f32x4 acc[4][4];
#pragma unroll
  for (int i = 0; i < 4; ++i)
#pragma unroll
    for (int j = 0; j < 4; ++j) acc[i][j] = (f32x4){0.f, 0.f, 0.f, 0.f};

  auto load16 = [&](uint4 (&buf)[16], int k0) {
#pragma unroll
    for (int i = 0; i < 4; ++i) {
      int rr = i * 32 + srow;
      int kg = ((sslot ^ (rr & 7)) << 3);
      size_t ro = (size_t)rr * LL + k0 + kg;
      buf[i] = *(const uint4*)(Ah + ro);
      buf[4 + i] = *(const uint4*)(Al + ro);
      buf[8 + i] = *(const uint4*)(Bh + ro);
      buf[12 + i] = *(const uint4*)(Bl + ro);
    }
  };
  auto store16 = [&](uint4 (&buf)[16]) {
#pragma unroll
    for (int i = 0; i < 4; ++i) {
      int off = (i * 32 + srow) * 128 + sslot * 16;
      *(uint4*)(AH + off) = buf[i];
      *(uint4*)(AL + off) = buf[4 + i];
      *(uint4*)(BH + off) = buf[8 + i];
      *(uint4*)(BL + off) = buf[12 + i];
    }
  };

  uint4 bufA[16], bufB[16];
  load16(bufA, 0);
  for (int kt = 0; kt < 6; kt += 2) {
    __syncthreads();
    store16(bufA);
    if (kt + 1 < 6) load16(bufB, (kt + 1) * 64);
    __syncthreads();
    compute_tile(AH, AL, BH, BL, lane, wr, wc, acc);
    __syncthreads();
    store16(bufB);
    if (kt + 2 < 6) load16(bufA, (kt + 2) * 64);
    __syncthreads();
    compute_tile(AH, AL, BH, BL, lane, wr, wc, acc);
  }

  const float* rmk = rowmask + (size_t)b * LL;
  float* Og = out + (size_t)b * (LL * DD);
  int rbase = m0 + wr + ((lane >> 4) << 2);
  int cbase = n0 + wc + (lane & 15);
#pragma unroll
  for (int i = 0; i < 4; ++i) {
#pragma unroll
    for (int r = 0; r < 4; ++r) {
      int row = rbase + i * 16 + r;
      float mk = rmk[row];
#pragma unroll
      for (int j = 0; j < 4; ++j)
        Og[(size_t)row * DD + cbase + j * 16] = acc[i][j][r] * mk;
    }
  }
}

// ---------- launch ----------
extern "C" void kernel_launch(void* const* d_in, const int* in_sizes, int n_in,
                              void* d_out, int out_size, void* d_ws, size_t ws_size,
                              hipStream_t stream) {
  const float* pre = (const float*)d_in[0];
  const float* pmask = (const float*)d_in[1];
  const float* hypo = (const float*)d_in[2];
  const float* hmask = (const float*)d_in[3];
  float* out = (float*)d_out;
  char* ws = (char*)d_ws;

  // Workspace layout (bytes). Total ~531 MB.
  const size_t S4 = 75497472ull;   // sim fp32: 128*384*384*4
  const size_t S2 = 37748736ull;   // one P plane: 128*384*384*2
  const size_t E2 = 75497472ull;   // one transposed feature plane: 128*768*384*2
  const size_t R4 = 196608ull;     // stats vector: 128*384*4
  float* sim = (float*)ws;
  unsigned short* P1H = (unsigned short*)(ws + S4);
  unsigned short* P1L = (unsigned short*)(ws + S4 + S2);
  unsigned short* P2H = (unsigned short*)(ws + S4 + 2 * S2);
  unsigned short* P2L = (unsigned short*)(ws + S4 + 3 * S2);
  unsigned short* hTH = (unsigned short*)(ws + S4 + 4 * S2);
  unsigned short* hTL = (unsigned short*)(ws + S4 + 4 * S2 + E2);
  unsigned short* pTH = (unsigned short*)(ws + S4 + 4 * S2 + 2 * E2);
  unsigned short* pTL = (unsigned short*)(ws + S4 + 4 * S2 + 3 * E2);
  char* st = ws + S4 + 4 * S2 + 4 * E2;
  float* rmax = (float*)(st);
  float* rinv = (float*)(st + R4);
  float* cmax = (float*)(st + 2 * R4);
  float* cinv = (float*)(st + 3 * R4);
  float* cmax_p = (float*)(st + 4 * R4);
  float* csum_p = (float*)(st + 8 * R4);

  transpose_split<<<dim3(NB, 12, 24), 256, 0, stream>>>(hypo, hTH, hTL);
  transpose_split<<<dim3(NB, 12, 24), 256, 0, stream>>>(pre, pTH, pTL);
  sim_gemm<<<NB * 9, 256, 0, stream>>>(pre, hypo, sim);
  row_stats<<<NB * LL / 4, 256, 0, stream>>>(sim, hmask, rmax, rinv);
  col_stats_part<<<dim3(NB, 4), 384, 0, stream>>>(sim, pmask, cmax_p, csum_p);
  col_combine<<<NB * LL / 256, 256, 0, stream>>>(cmax_p, csum_p, cmax, cinv);
  softmax_apply<<<dim3(NB, 6, 6), 256, 0, stream>>>(sim, hmask, pmask, rmax, rinv, cmax, cinv,
                                                    P1H, P1L, P2H, P2L);
  pv_gemm<<<dim3(NB, 3, 6), 256, 0, stream>>>(P1H, P1L, hTH, hTL, pmask, out);
  pv_gemm<<<dim3(NB, 3, 6), 256, 0, stream>>>(P2H, P2L, pTH, pTL, hmask, out + 37748736ull);
}

// Round 3
// 1398.172 us; speedup vs baseline: 1.2001x; 1.2001x over previous
//
#include <hip/hip_runtime.h>
#include <hip/hip_bf16.h>
#include <cstdint>

// Problem constants
#define NB 128
#define LL 384   // LP == LH == 384
#define DD 768
#define NEG_BIAS 1e13f

typedef __attribute__((ext_vector_type(8))) short bf16x8;
typedef __attribute__((ext_vector_type(4))) float f32x4;

// ---------- bf16 helpers (RNE, matches HW conversion) ----------
__device__ __forceinline__ unsigned short f2bf(float f) {
  unsigned int u = __float_as_uint(f);
  return (unsigned short)((u + 0x7fffu + ((u >> 16) & 1u)) >> 16);
}
__device__ __forceinline__ float bf2f(unsigned short v) {
  return __uint_as_float(((unsigned int)v) << 16);
}
__device__ __forceinline__ void split2(float f, unsigned short& h, unsigned short& l) {
  h = f2bf(f);
  l = f2bf(f - bf2f(h));
}

// ---------- shared MFMA tile core ----------
// LDS planes: [128 rows][64 k] bf16, row pitch 128 B, 16B-slot XOR swizzle: slot ^= (row&7)
__device__ __forceinline__ void mfma3(f32x4& acc, bf16x8 ah, bf16x8 al, bf16x8 bh, bf16x8 bl) {
  acc = __builtin_amdgcn_mfma_f32_16x16x32_bf16(ah, bh, acc, 0, 0, 0);
  acc = __builtin_amdgcn_mfma_f32_16x16x32_bf16(ah, bl, acc, 0, 0, 0);
  acc = __builtin_amdgcn_mfma_f32_16x16x32_bf16(al, bh, acc, 0, 0, 0);
}

__device__ __forceinline__ void compute_tile(const char* AH, const char* AL,
                                             const char* BH, const char* BL,
                                             int lane, int wr, int wc, f32x4 (&acc)[4][4]) {
  const int q16 = (lane >> 4) * 16;   // 16B k-slot base within 64-k row (x2 ks)
  const int r15 = lane & 15;
#pragma unroll
  for (int ks = 0; ks < 2; ++ks) {
    bf16x8 ah[4], al[4], bh[4], bl[4];
    int koff = ks * 64 + q16;
#pragma unroll
    for (int i = 0; i < 4; ++i) {
      int ar = wr + i * 16 + r15;
      int ao = ar * 128 + (koff ^ ((ar & 7) << 4));
      ah[i] = *(const bf16x8*)(AH + ao);
      al[i] = *(const bf16x8*)(AL + ao);
      int br = wc + i * 16 + r15;
      int bo = br * 128 + (koff ^ ((br & 7) << 4));
      bh[i] = *(const bf16x8*)(BH + bo);
      bl[i] = *(const bf16x8*)(BL + bo);
    }
#pragma unroll
    for (int i = 0; i < 4; ++i)
#pragma unroll
      for (int j = 0; j < 4; ++j)
        mfma3(acc[i][j], ah[i], al[i], bh[j], bl[j]);
  }
}

// ---------- kernel 1: transpose + bf16 hi/lo split ----------
// X: [B][384][768] fp32  ->  TH/TL: [B][768][384] bf16 bits
__global__ __launch_bounds__(256) void transpose_split(
    const float* __restrict__ X, unsigned short* __restrict__ TH, unsigned short* __restrict__ TL) {
  __shared__ float lds[32][33];
  int b = blockIdx.x, ti = blockIdx.y, tj = blockIdx.z;
  int l0 = ti * 32, d0 = tj * 32;
  int t = threadIdx.x;
  int r = t >> 5, c = t & 31;
#pragma unroll
  for (int k = 0; k < 4; ++k) {
    int rr = r + k * 8;
    lds[rr][c] = X[((size_t)b * LL + l0 + rr) * DD + d0 + c];
  }
  __syncthreads();
#pragma unroll
  for (int k = 0; k < 4; ++k) {
    int rr = r + k * 8;                       // local d index
    float v = lds[c][rr];                     // X[b][l0+c][d0+rr]
    unsigned short h, l;
    split2(v, h, l);
    size_t o = ((size_t)b * DD + d0 + rr) * LL + l0 + c;
    TH[o] = h;
    TL[o] = l;
  }
}

// ---------- kernel 2: sim = pre @ hypo^T (per batch), fp32 out via bf16x3 split ----------
// grid: (9, NB) — x = tile (consecutive blocks share batch b for L2/L3 locality)
__global__ __launch_bounds__(256, 2) void sim_gemm(
    const float* __restrict__ pre, const float* __restrict__ hypo, float* __restrict__ sim) {
  int tt = blockIdx.x, b = blockIdx.y;
  int tp = tt / 3, th = tt % 3;
  int t = threadIdx.x, lane = t & 63, w = t >> 6;
  int wr = (w >> 1) * 64, wc = (w & 1) * 64;
  __shared__ char lds[65536];
  char *AH = lds, *AL = lds + 16384, *BH = lds + 32768, *BL = lds + 49152;
  const float* Ag = pre + ((size_t)b * LL + tp * 128) * DD;
  const float* Bg = hypo + ((size_t)b * LL + th * 128) * DD;
  int srow = t >> 4, sc4 = t & 15;

  f32x4 acc[4][4];
#pragma unroll
  for (int i = 0; i < 4; ++i)
#pragma unroll
    for (int j = 0; j < 4; ++j) acc[i][j] = (f32x4){0.f, 0.f, 0.f, 0.f};

  auto load16 = [&](float4 (&av)[8], float4 (&bv)[8], int k0) {
#pragma unroll
    for (int pass = 0; pass < 8; ++pass) {
      int rr = pass * 16 + srow;
      av[pass] = *(const float4*)(Ag + (size_t)rr * DD + k0 + sc4 * 4);
      bv[pass] = *(const float4*)(Bg + (size_t)rr * DD + k0 + sc4 * 4);
    }
  };
  auto store16 = [&](float4 (&av)[8], float4 (&bv)[8]) {
#pragma unroll
    for (int pass = 0; pass < 8; ++pass) {
      int rr = pass * 16 + srow;
      int off = rr * 128 + ((sc4 * 8) ^ ((rr & 7) << 4));
      unsigned short h0, h1, h2, h3, l0, l1, l2, l3;
      split2(av[pass].x, h0, l0); split2(av[pass].y, h1, l1);
      split2(av[pass].z, h2, l2); split2(av[pass].w, h3, l3);
      *(uint2*)(AH + off) = make_uint2(((unsigned)h1 << 16) | h0, ((unsigned)h3 << 16) | h2);
      *(uint2*)(AL + off) = make_uint2(((unsigned)l1 << 16) | l0, ((unsigned)l3 << 16) | l2);
      split2(bv[pass].x, h0, l0); split2(bv[pass].y, h1, l1);
      split2(bv[pass].z, h2, l2); split2(bv[pass].w, h3, l3);
      *(uint2*)(BH + off) = make_uint2(((unsigned)h1 << 16) | h0, ((unsigned)h3 << 16) | h2);
      *(uint2*)(BL + off) = make_uint2(((unsigned)l1 << 16) | l0, ((unsigned)l3 << 16) | l2);
    }
  };

  float4 avA[8], bvA[8], avB[8], bvB[8];
  load16(avA, bvA, 0);
  for (int kt = 0; kt < 12; kt += 2) {
    __syncthreads();
    store16(avA, bvA);
    if (kt + 1 < 12) load16(avB, bvB, (kt + 1) * 64);
    __syncthreads();
    compute_tile(AH, AL, BH, BL, lane, wr, wc, acc);
    __syncthreads();
    store16(avB, bvB);
    if (kt + 2 < 12) load16(avA, bvA, (kt + 2) * 64);
    __syncthreads();
    compute_tile(AH, AL, BH, BL, lane, wr, wc, acc);
  }

  float* Cg = sim + (size_t)b * (LL * LL);
  int rbase = tp * 128 + wr + ((lane >> 4) << 2);
  int cbase = th * 128 + wc + (lane & 15);
#pragma unroll
  for (int i = 0; i < 4; ++i)
#pragma unroll
    for (int j = 0; j < 4; ++j)
#pragma unroll
      for (int r = 0; r < 4; ++r)
        Cg[(size_t)(rbase + i * 16 + r) * LL + cbase + j * 16] = acc[i][j][r];
}

// ---------- kernel 3: sim -> simT (fp32, per batch) ----------
__global__ __launch_bounds__(256) void transpose_f32(
    const float* __restrict__ X, float* __restrict__ Y) {
  __shared__ float lds[32][33];
  int tj = blockIdx.x, ti = blockIdx.y, b = blockIdx.z;
  int r0 = ti * 32, c0 = tj * 32;
  int t = threadIdx.x, r = t >> 5, c = t & 31;
  const float* Xb = X + (size_t)b * (LL * LL);
  float* Yb = Y + (size_t)b * (LL * LL);
#pragma unroll
  for (int k = 0; k < 4; ++k)
    lds[r + k * 8][c] = Xb[(size_t)(r0 + r + k * 8) * LL + c0 + c];
  __syncthreads();
#pragma unroll
  for (int k = 0; k < 4; ++k)
    Yb[(size_t)(c0 + r + k * 8) * LL + r0 + c] = lds[c][r + k * 8];
}

// ---------- kernel 4: row stats (masked softmax max + 1/sum along k) ----------
// Serves BOTH directions: row-softmax of sim (mask=hmask) and of simT (mask=pmask).
__global__ __launch_bounds__(256) void row_stats(
    const float* __restrict__ S, const float* __restrict__ kmask,
    float* __restrict__ rmax, float* __restrict__ rinv) {
  int gw = blockIdx.x * 4 + (threadIdx.x >> 6);
  int lane = threadIdx.x & 63;
  int b = gw / LL;
  const float* row = S + (size_t)gw * LL;
  const float* km = kmask + (size_t)b * LL;
  float x[6];
  float m = -3.0e38f;
#pragma unroll
  for (int i = 0; i < 6; ++i) {
    float s = row[i * 64 + lane];
    float mk = km[i * 64 + lane];
    x[i] = s * mk + (mk - 1.f) * NEG_BIAS;
    m = fmaxf(m, x[i]);
  }
#pragma unroll
  for (int off = 32; off; off >>= 1) m = fmaxf(m, __shfl_xor(m, off));
  float sum = 0.f;
#pragma unroll
  for (int i = 0; i < 6; ++i) sum += expf(x[i] - m);
#pragma unroll
  for (int off = 32; off; off >>= 1) sum += __shfl_xor(sum, off);
  if (lane == 0) { rmax[gw] = m; rinv[gw] = 1.f / sum; }
}

// ---------- kernel 5: out[b][m][n] = (softmax(S) @ V) * outmask ----------
// S: [B][384][384] fp32 logits, k-contiguous rows. Softmax applied in-register
// during LDS staging using precomputed (rmax, rinv) and k-mask.
// B planes: [B][768][384] bf16 hi/lo, k-contiguous rows.
// grid: (6 tn, 3 tm, NB b) — consecutive blocks share the A slab.
__global__ __launch_bounds__(256, 2) void pv_gemm_fused(
    const float* __restrict__ S, const float* __restrict__ kmask,
    const float* __restrict__ rmax, const float* __restrict__ rinv,
    const unsigned short* __restrict__ BHp, const unsigned short* __restrict__ BLp,
    const float* __restrict__ outmask, float* __restrict__ out) {
  int tn = blockIdx.x, tm = blockIdx.y, b = blockIdx.z;
  int m0 = tm * 128, n0 = tn * 128;
  int t = threadIdx.x, lane = t & 63, w = t >> 6;
  int wr = (w >> 1) * 64, wc = (w & 1) * 64;
  __shared__ char lds[65536];
  char *AH = lds, *AL = lds + 16384, *BH = lds + 32768, *BL = lds + 49152;
  const float* Sg = S + (size_t)b * (LL * LL) + (size_t)m0 * LL;
  const float* km = kmask + (size_t)b * LL;
  const unsigned short* Bh = BHp + (size_t)b * (DD * LL) + (size_t)n0 * LL;
  const unsigned short* Bl = BLp + (size_t)b * (DD * LL) + (size_t)n0 * LL;
  int srow = t >> 3, sslot = t & 7;
  const int aslotx = ((sslot ^ (srow & 7)) << 4);  // swizzled LDS A slot (row&7 == srow&7)

  // Per-thread row stats: rows i*32+srow, fixed for the whole block.
  float rm[4], ri[4];
#pragma unroll
  for (int i = 0; i < 4; ++i) {
    int row = m0 + i * 32 + srow;
    rm[i] = rmax[(size_t)b * LL + row];
    ri[i] = rinv[(size_t)b * LL + row];
  }

  f32x4 acc[4][4];
#pragma unroll
  for (int i = 0; i < 4; ++i)
#pragma unroll
    for (int j = 0; j < 4; ++j) acc[i][j] = (f32x4){0.f, 0.f, 0.f, 0.f};

  // load: raw sim fp32 + k-mask into regs (linear k); B planes with global pre-XOR
  auto loadS = [&](float4 (&sa)[4][2], float4 (&mk)[2], uint4 (&bb)[8], int k0) {
    mk[0] = *(const float4*)(km + k0 + sslot * 8);
    mk[1] = *(const float4*)(km + k0 + sslot * 8 + 4);
#pragma unroll
    for (int i = 0; i < 4; ++i) {
      int row = i * 32 + srow;
      const float* p = Sg + (size_t)row * LL + k0 + sslot * 8;
      sa[i][0] = *(const float4*)(p);
      sa[i][1] = *(const float4*)(p + 4);
      int kg = ((sslot ^ (row & 7)) << 3);
      size_t ro = (size_t)row * LL + k0 + kg;
      bb[i] = *(const uint4*)(Bh + ro);
      bb[4 + i] = *(const uint4*)(Bl + ro);
    }
  };
  // store: softmax + split A into swizzled LDS; B linear (pre-XOR'd source)
  auto storeS = [&](float4 (&sa)[4][2], float4 (&mk)[2], uint4 (&bb)[8]) {
    float mv[8] = {mk[0].x, mk[0].y, mk[0].z, mk[0].w, mk[1].x, mk[1].y, mk[1].z, mk[1].w};
#pragma unroll
    for (int i = 0; i < 4; ++i) {
      int row = i * 32 + srow;
      float xv[8] = {sa[i][0].x, sa[i][0].y, sa[i][0].z, sa[i][0].w,
                     sa[i][1].x, sa[i][1].y, sa[i][1].z, sa[i][1].w};
      unsigned short h[8], l[8];
#pragma unroll
      for (int e = 0; e < 8; ++e) {
        float xx = xv[e] * mv[e] + (mv[e] - 1.f) * NEG_BIAS;
        float p1 = __expf(xx - rm[i]) * ri[i];
        split2(p1, h[e], l[e]);
      }
      uint4 hv, lv;
      hv.x = ((unsigned)h[1] << 16) | h[0]; hv.y = ((unsigned)h[3] << 16) | h[2];
      hv.z = ((unsigned)h[5] << 16) | h[4]; hv.w = ((unsigned)h[7] << 16) | h[6];
      lv.x = ((unsigned)l[1] << 16) | l[0]; lv.y = ((unsigned)l[3] << 16) | l[2];
      lv.z = ((unsigned)l[5] << 16) | l[4]; lv.w = ((unsigned)l[7] << 16) | l[6];
      int offa = row * 128 + aslotx;
      *(uint4*)(AH + offa) = hv;
      *(uint4*)(AL + offa) = lv;
      int offb = row * 128 + sslot * 16;
      *(uint4*)(BH + offb) = bb[i];
      *(uint4*)(BL + offb) = bb[4 + i];
    }
  };

  float4 saA[4][2], saB[4][2], mkA[2], mkB[2];
  uint4 bbA[8], bbB[8];
  loadS(saA, mkA, bbA, 0);
  for (int kt = 0; kt < 6; kt += 2) {
    __syncthreads();
    storeS(saA, mkA, bbA);
    if (kt + 1 < 6) loadS(saB, mkB, bbB, (kt + 1) * 64);
    __syncthreads();
    compute_tile(AH, AL, BH, BL, lane, wr, wc, acc);
    __syncthreads();
    storeS(saB, mkB, bbB);
    if (kt + 2 < 6) loadS(saA, mkA, bbA, (kt + 2) * 64);
    __syncthreads();
    compute_tile(AH, AL, BH, BL, lane, wr, wc, acc);
  }

  const float* omk = outmask + (size_t)b * LL;
  float* Og = out + (size_t)b * (LL * DD);
  int rbase = m0 + wr + ((lane >> 4) << 2);
  int cbase = n0 + wc + (lane & 15);
#pragma unroll
  for (int i = 0; i < 4; ++i) {
#pragma unroll
    for (int r = 0; r < 4; ++r) {
      int row = rbase + i * 16 + r;
      float mkv = omk[row];
#pragma unroll
      for (int j = 0; j < 4; ++j)
        Og[(size_t)row * DD + cbase + j * 16] = acc[i][j][r] * mkv;
    }
  }
}

// ---------- launch ----------
extern "C" void kernel_launch(void* const* d_in, const int* in_sizes, int n_in,
                              void* d_out, int out_size, void* d_ws, size_t ws_size,
                              hipStream_t stream) {
  const float* pre = (const float*)d_in[0];
  const float* pmask = (const float*)d_in[1];
  const float* hypo = (const float*)d_in[2];
  const float* hmask = (const float*)d_in[3];
  float* out = (float*)d_out;
  char* ws = (char*)d_ws;

  // Workspace layout (bytes). Total ~454 MB.
  const size_t S4 = 75497472ull;   // sim fp32: 128*384*384*4 (also plane size: 128*768*384*2)
  const size_t R4 = 196608ull;     // stats vector: 128*384*4
  float* sim = (float*)ws;
  float* simT = (float*)(ws + S4);
  unsigned short* hTH = (unsigned short*)(ws + 2 * S4);
  unsigned short* hTL = (unsigned short*)(ws + 3 * S4);
  unsigned short* pTH = (unsigned short*)(ws + 4 * S4);
  unsigned short* pTL = (unsigned short*)(ws + 5 * S4);
  char* st = ws + 6 * S4;
  float* rmax = (float*)(st);
  float* rinv = (float*)(st + R4);
  float* cmax = (float*)(st + 2 * R4);
  float* cinv = (float*)(st + 3 * R4);

  transpose_split<<<dim3(NB, 12, 24), 256, 0, stream>>>(hypo, hTH, hTL);
  transpose_split<<<dim3(NB, 12, 24), 256, 0, stream>>>(pre, pTH, pTL);
  sim_gemm<<<dim3(9, NB), 256, 0, stream>>>(pre, hypo, sim);
  transpose_f32<<<dim3(12, 12, NB), 256, 0, stream>>>(sim, simT);
  row_stats<<<NB * LL / 4, 256, 0, stream>>>(sim, hmask, rmax, rinv);
  row_stats<<<NB * LL / 4, 256, 0, stream>>>(simT, pmask, cmax, cinv);
  pv_gemm_fused<<<dim3(6, 3, NB), 256, 0, stream>>>(sim, hmask, rmax, rinv,
                                                    hTH, hTL, pmask, out);
  pv_gemm_fused<<<dim3(6, 3, NB), 256, 0, stream>>>(simT, pmask, cmax, cinv,
                                                    pTH, pTL, hmask, out + 37748736ull);
}